// Round 17
// baseline (187.275 us; speedup 1.0000x reference)
//
#include <hip/hip_runtime.h>
#include <hip/hip_bf16.h>

#define U_DIM 1024
#define H_DIM 4096
#define N_DIM 8192   // 2H
#define K_DIM 4096   // = H

#define BM 128
#define BN 256
#define BK 64
#define NT (K_DIM / BK)            // 64 K-tiles
#define SLOTB (BM*BK*2 + BN*BK*2)  // 16KB A + 32KB B = 49152 B per ring slot

typedef __attribute__((ext_vector_type(8))) short bf16x8;
typedef __attribute__((ext_vector_type(4))) float f32x4;

__device__ inline unsigned short f2bf(float f) {
  union { float f; unsigned u; } a; a.f = f;
  unsigned r = a.u + 0x7fffu + ((a.u >> 16) & 1u);  // RNE
  return (unsigned short)(r >> 16);
}

__device__ inline void gload_lds16(const void* g, void* l) {
  __builtin_amdgcn_global_load_lds(
      (const __attribute__((address_space(1))) unsigned*)(g),
      (__attribute__((address_space(3))) unsigned*)(l), 16, 0, 0);
}

// ------- fused pre-pass: ssm_proj [K][N] fp32 -> Bt [N][K] bf16  AND  x -> bf16 -------
#define TRANS_BLOCKS ((N_DIM / 64) * (K_DIM / 64))          // 8192
#define CONV_BLOCKS  ((U_DIM * H_DIM) / (256 * 8))          // 2048
__global__ __launch_bounds__(256) void prep_kernel(
    const float* __restrict__ B, unsigned short* __restrict__ Bt,
    const float* __restrict__ x, unsigned short* __restrict__ xb) {
  const int tid = threadIdx.x;
  if (blockIdx.x >= TRANS_BLOCKS) {
    size_t i = (size_t)(blockIdx.x - TRANS_BLOCKS) * 256 + tid;
    float4 v0 = ((const float4*)x)[2 * i];
    float4 v1 = ((const float4*)x)[2 * i + 1];
    union { bf16x8 v; unsigned short u[8]; } o;
    o.u[0] = f2bf(v0.x); o.u[1] = f2bf(v0.y); o.u[2] = f2bf(v0.z); o.u[3] = f2bf(v0.w);
    o.u[4] = f2bf(v1.x); o.u[5] = f2bf(v1.y); o.u[6] = f2bf(v1.z); o.u[7] = f2bf(v1.w);
    ((bf16x8*)xb)[i] = o.v;
    return;
  }
  __shared__ float tile[64][65];
  const int kt = blockIdx.x & 63;
  const int nt = blockIdx.x >> 6;
  const int k0 = kt * 64, n0 = nt * 64;
  const int lr = tid >> 4;
  const int lc = (tid & 15) * 4;
#pragma unroll
  for (int it = 0; it < 4; ++it) {
    int r = it * 16 + lr;
    float4 v = *(const float4*)(&B[(size_t)(k0 + r) * N_DIM + n0 + lc]);
    tile[r][lc + 0] = v.x; tile[r][lc + 1] = v.y;
    tile[r][lc + 2] = v.z; tile[r][lc + 3] = v.w;
  }
  __syncthreads();
  const int sc = tid & 7;
  const int sr = tid >> 3;
#pragma unroll
  for (int it = 0; it < 2; ++it) {
    int rn = it * 32 + sr;
    union { bf16x8 v; unsigned short u[8]; } o;
#pragma unroll
    for (int j = 0; j < 8; ++j) o.u[j] = f2bf(tile[sc * 8 + j][rn]);
    *(bf16x8*)(&Bt[(size_t)(n0 + rn) * K_DIM + k0 + sc * 8]) = o.v;
  }
}

// ------- bf16 MFMA GEMM: 8 compute waves (r12 K-loop) + 2 DEDICATED COPY WAVES -------
// Producer/consumer split: waves 0-7 run r12's proven counted-vmcnt ring K-loop
// (untouched); waves 8-9 (128 lanes) stream the acc-independent epilogue work
// DURING the K-loop: per iter, 128 float4 = {read cs1..3 + wts/bias, write
// ns0..2, write pc = w0*c1+w1*c2+w2*c3+bias into out[]}. vmcnt is PER-WAVE, so
// copy traffic cannot perturb the compute waves' counted ledger (r9/r10's
// failure mode). Both paths execute the same per-iter s_barrier. The serial
// tail shrinks to {read pc, += w3*xp, write out, write ns3} = 96MB (was 256MB).
template <bool FUSE>
__global__ __launch_bounds__(640, 1) void gemm_conv_kernel(
    const unsigned short* __restrict__ Abf,   // [U][K] bf16
    const unsigned short* __restrict__ Btbf,  // [N][K] bf16
    const float* __restrict__ conv_states,    // [4][U][N]
    const float* __restrict__ conv_wts,       // [4][N]
    const float* __restrict__ conv_bias,      // [N]
    float* __restrict__ out,                  // [U][N]
    float* __restrict__ ns)                   // [4][U][N] new_states base
{
  __shared__ char smem[3 * SLOTB];   // 144KB ring; reused as 128KB C-buf

  const int orig = blockIdx.x;                    // grid 256 = 8 XCD x 32
  const int bid  = (orig & 7) * 32 + (orig >> 3); // XCD-chunked swizzle
  const int brow = bid & 7;                       // 8 row-blocks  (BM=128)
  const int bcol = bid >> 3;                      // 32 col-blocks (BN=256)
  const int tid  = threadIdx.x;
  const int lane = tid & 63;
  const int wid  = tid >> 6;             // 0..9
  const bool is_compute = (wid < 8);
  const int wr = (wid >> 2) & 1;         // 0..1 -> 64-row group (compute)
  const int wc = wid & 3;                // 0..3 -> 64-col group (compute)

  f32x4 acc[4][4];
#pragma unroll
  for (int m = 0; m < 4; ++m)
#pragma unroll
    for (int n = 0; n < 4; ++n)
#pragma unroll
      for (int r = 0; r < 4; ++r) acc[m][n][r] = 0.0f;

  // ---- staging (compute waves, tid<512): 6 x gload_lds of 8KB (512 x 16B)
  const int rowa = (tid & 511) >> 3;               // 0..63
  const int gsl  = (tid & 7) ^ (rowa & 7);         // pre-swizzled global 16B slot
  const int tid16 = (tid & 511) * 16;
  const unsigned short* gA0 = Abf  + (size_t)(brow * BM + rowa) * K_DIM + gsl * 8;
  const unsigned short* gA1 = gA0 + (size_t)64 * K_DIM;
  const unsigned short* gB0 = Btbf + (size_t)(bcol * BN + rowa) * K_DIM + gsl * 8;
  const unsigned short* gB1 = gB0 + (size_t)64  * K_DIM;
  const unsigned short* gB2 = gB0 + (size_t)128 * K_DIM;
  const unsigned short* gB3 = gB0 + (size_t)192 * K_DIM;

#define STAGE(kt, base) do {                               \
    const size_t ko = (size_t)(kt) * BK;                   \
    gload_lds16(gA0 + ko, (base) + tid16);                 \
    gload_lds16(gA1 + ko, (base) + 8192  + tid16);         \
    gload_lds16(gB0 + ko, (base) + 16384 + tid16);         \
    gload_lds16(gB1 + ko, (base) + 24576 + tid16);         \
    gload_lds16(gB2 + ko, (base) + 32768 + tid16);         \
    gload_lds16(gB3 + ko, (base) + 40960 + tid16);         \
  } while (0)

  // ---- fragment read offsets (LDS rows 128B; slot^(row&7), row&7 == l15&7)
  const int l15 = lane & 15;
  const int fs  = lane >> 4;
  const int rsw = l15 & 7;
  int aoff[4], boff[4];
#pragma unroll
  for (int m = 0; m < 4; ++m) aoff[m] = (wr * 64 + m * 16 + l15) * 128;
#pragma unroll
  for (int n = 0; n < 4; ++n) boff[n] = (wc * 64 + n * 16 + l15) * 128;

  // ---- epilogue-stream pointers (used by copy waves during the loop)
  const size_t PL4 = (size_t)U_DIM * (N_DIM / 4);
  const int    N4  = N_DIM / 4;
  const float4* cs1 = (const float4*)conv_states + PL4;
  const float4* cs2 = (const float4*)conv_states + 2 * PL4;
  const float4* cs3 = (const float4*)conv_states + 3 * PL4;
  float4* out4 = (float4*)out;
  float4* ns0 = (float4*)ns;
  float4* ns1 = ns0 + PL4;
  float4* ns2 = ns0 + 2 * PL4;
  float4* ns3 = ns0 + 3 * PL4;
  const float4* wt4 = (const float4*)conv_wts;
  const float4* bi4 = (const float4*)conv_bias;

  // ---- prologue: stage tiles 0,1; publish tile 0 (tile 1's 6 DMAs in flight)
  if (is_compute) {
    STAGE(0, smem);
    STAGE(1, smem + SLOTB);
    asm volatile("s_waitcnt vmcnt(6)" ::: "memory");
  }
  __builtin_amdgcn_s_barrier();
  __builtin_amdgcn_sched_barrier(0);

  int s0 = 0, s2 = 2;   // slot of tile t, slot for tile t+2
#pragma unroll 1
  for (int t = 0; t < NT; ++t) {
    if (is_compute) {
      if (t + 2 < NT) STAGE(t + 2, smem + s2 * SLOTB);

      const char* curA = smem + s0 * SLOTB;
      const char* curB = curA + 16384;
#pragma unroll
      for (int kh = 0; kh < 2; ++kh) {
        const int ksl = ((kh * 4 + fs) ^ rsw) * 16;
        bf16x8 af[4], bv[4];
#pragma unroll
        for (int m = 0; m < 4; ++m) af[m] = *(const bf16x8*)(curA + aoff[m] + ksl);
#pragma unroll
        for (int n = 0; n < 4; ++n) bv[n] = *(const bf16x8*)(curB + boff[n] + ksl);
        __builtin_amdgcn_s_setprio(1);
#pragma unroll
        for (int m = 0; m < 4; ++m)
#pragma unroll
          for (int n = 0; n < 4; ++n)
            acc[m][n] = __builtin_amdgcn_mfma_f32_16x16x32_bf16(af[m], bv[n], acc[m][n], 0, 0, 0);
        __builtin_amdgcn_s_setprio(0);
      }

      if (t + 2 < NT) asm volatile("s_waitcnt vmcnt(6) lgkmcnt(0)" ::: "memory");
      else            asm volatile("s_waitcnt vmcnt(0) lgkmcnt(0)" ::: "memory");
    } else {
      // ---- copy waves: 128 lanes stream 128 float4 (2 rows) per iter ----
      const int ctid = tid - 512;            // 0..127
      const int g    = t * 128 + ctid;       // f4 index in 128x64-f4 tile
      const int lrow = g >> 6, d4 = g & 63;
      const int dcol4 = bcol * N4 / 1 * 0 + bcol * (BN / 4) + d4;
      const size_t gf4 = (size_t)(brow * BM + lrow) * N4 + dcol4;
      const float4 c1 = cs1[gf4], c2 = cs2[gf4], c3 = cs3[gf4];
      const float4 w0 = wt4[dcol4];
      const float4 w1 = wt4[N4 + dcol4];
      const float4 w2 = wt4[2 * N4 + dcol4];
      const float4 bs = bi4[dcol4];
      float4 pc;
      pc.x = fmaf(w0.x, c1.x, fmaf(w1.x, c2.x, fmaf(w2.x, c3.x, bs.x)));
      pc.y = fmaf(w0.y, c1.y, fmaf(w1.y, c2.y, fmaf(w2.y, c3.y, bs.y)));
      pc.z = fmaf(w0.z, c1.z, fmaf(w1.z, c2.z, fmaf(w2.z, c3.z, bs.z)));
      pc.w = fmaf(w0.w, c1.w, fmaf(w1.w, c2.w, fmaf(w2.w, c3.w, bs.w)));
      out4[gf4] = pc;                        // pc staged; tail adds w3*xp
      if (FUSE) { ns0[gf4] = c1; ns1[gf4] = c2; ns2[gf4] = c3; }
    }
    __builtin_amdgcn_s_barrier();
    __builtin_amdgcn_sched_barrier(0);

    s0 = (s0 == 2) ? 0 : s0 + 1;
    s2 = (s2 == 2) ? 0 : s2 + 1;
  }
#undef STAGE

  // ---- epilogue: acc -> LDS C-buf (f32 [128][256], col ^ (fs<<3)) ----
  float* cbuf = (float*)smem;
  if (is_compute) {
#pragma unroll
    for (int m = 0; m < 4; ++m)
#pragma unroll
      for (int n = 0; n < 4; ++n) {
        const int colb = (wc * 64 + n * 16 + l15) ^ (fs << 3);
#pragma unroll
        for (int r = 0; r < 4; ++r) {
          const int row = wr * 64 + m * 16 + fs * 4 + r;
          cbuf[row * 256 + colb] = acc[m][n][r];
        }
      }
  }
  __syncthreads();   // drains copy waves' stores + compute waves' ds_writes

  // ---- tail: out = pc(out) + w3*xp ; ns3 = xp   (96MB, float4, 13 passes) ----
#pragma unroll 1
  for (int p = 0; p < 13; ++p) {
    const int g = p * 640 + tid;
    if (g < 8192) {
      const int lrow = g >> 6, d4 = g & 63;
      const int fsr  = (lrow >> 2) & 3;
      const float4 xp4 = *(const float4*)&cbuf[lrow * 256 + ((d4 * 4) ^ (fsr << 3))];
      const int dcol4 = bcol * (BN / 4) + d4;
      const size_t gf4 = (size_t)(brow * BM + lrow) * N4 + dcol4;
      const float4 w3 = wt4[3 * N4 + dcol4];
      const float4 pc = out4[gf4];
      float4 o;
      o.x = fmaf(w3.x, xp4.x, pc.x);
      o.y = fmaf(w3.y, xp4.y, pc.y);
      o.z = fmaf(w3.z, xp4.z, pc.z);
      o.w = fmaf(w3.w, xp4.w, pc.w);
      out4[gf4] = o;
      ns3[gf4] = xp4;
    }
  }
}

extern "C" void kernel_launch(void* const* d_in, const int* in_sizes, int n_in,
                              void* d_out, int out_size, void* d_ws, size_t ws_size,
                              hipStream_t stream) {
  (void)in_sizes; (void)n_in; (void)out_size;
  const float* x           = (const float*)d_in[0];
  const float* ssm_proj    = (const float*)d_in[1];
  const float* conv_states = (const float*)d_in[2];
  const float* conv_wts    = (const float*)d_in[3];
  const float* conv_bias   = (const float*)d_in[4];
  float* outp = (float*)d_out;

  const size_t OUT_ELEMS = (size_t)U_DIM * N_DIM;        // 8M floats
  float* ns = outp + OUT_ELEMS;                          // new_states base

  const size_t BT_BYTES = (size_t)N_DIM * K_DIM * sizeof(unsigned short);  // 64MB
  const size_t XB_BYTES = (size_t)U_DIM * K_DIM * sizeof(unsigned short);  // 8MB
  const int GRID = (U_DIM / BM) * (N_DIM / BN);          // 256
  const int PREP_GRID = TRANS_BLOCKS + CONV_BLOCKS;      // 8192+2048

  if (ws_size >= BT_BYTES + XB_BYTES) {
    unsigned short* Btbf = (unsigned short*)d_ws;
    unsigned short* xbf  = (unsigned short*)((char*)d_ws + BT_BYTES);
    prep_kernel<<<PREP_GRID, 256, 0, stream>>>(ssm_proj, Btbf, x, xbf);
    gemm_conv_kernel<true><<<GRID, 640, 0, stream>>>(
        xbf, Btbf, conv_states, conv_wts, conv_bias, outp, ns);
  } else {
    // fallback: Bt/xbf scratch inside d_out's new_states region -> copy waves
    // skip ns0..2 stores (would corrupt Bt); d2d memcpy afterwards instead
    unsigned short* Btbf = (unsigned short*)ns;
    unsigned short* xbf  = (unsigned short*)(ns + 2 * OUT_ELEMS);
    prep_kernel<<<PREP_GRID, 256, 0, stream>>>(ssm_proj, Btbf, x, xbf);
    gemm_conv_kernel<false><<<GRID, 640, 0, stream>>>(
        xbf, Btbf, conv_states, conv_wts, conv_bias, outp, ns);
    hipMemcpyAsync(ns, conv_states + OUT_ELEMS, 3 * OUT_ELEMS * sizeof(float),
                   hipMemcpyDeviceToDevice, stream);
  }
}

// Round 18
// 169.152 us; speedup vs baseline: 1.1071x; 1.1071x over previous
//
#include <hip/hip_runtime.h>
#include <hip/hip_bf16.h>

#define U_DIM 1024
#define H_DIM 4096
#define N_DIM 8192   // 2H
#define K_DIM 4096   // = H

#define BM 128
#define BN 256
#define BK 64
#define NT (K_DIM / BK)            // 64 K-tiles
#define SLOTB (BM*BK*2 + BN*BK*2)  // 16KB A + 32KB B = 49152 B per ring slot

typedef __attribute__((ext_vector_type(8))) short bf16x8;
typedef __attribute__((ext_vector_type(4))) float f32x4;

__device__ inline unsigned short f2bf(float f) {
  union { float f; unsigned u; } a; a.f = f;
  unsigned r = a.u + 0x7fffu + ((a.u >> 16) & 1u);  // RNE
  return (unsigned short)(r >> 16);
}

__device__ inline void gload_lds16(const void* g, void* l) {
  __builtin_amdgcn_global_load_lds(
      (const __attribute__((address_space(1))) unsigned*)(g),
      (__attribute__((address_space(3))) unsigned*)(l), 16, 0, 0);
}

// ------- fused pre-pass: ssm_proj [K][N] fp32 -> Bt [N][K] bf16  AND  x -> bf16 -------
// Transpose tiles widened to 64K x 256N: wave reads one 1KB-CONTIGUOUS row per
// pass (was 4 x 256B segments). LDS fp32 [64][257] (65.8KB, 2 blocks/CU).
// Write-phase LDS col-reads: stride 257 -> (8*sc+rn) mod 32 = 2-way (free).
#define TRANS_BLOCKS ((K_DIM / 64) * (N_DIM / 256))         // 64*32 = 2048
#define CONV_BLOCKS  ((U_DIM * H_DIM) / (256 * 8))          // 2048
__global__ __launch_bounds__(256) void prep_kernel(
    const float* __restrict__ B, unsigned short* __restrict__ Bt,
    const float* __restrict__ x, unsigned short* __restrict__ xb) {
  const int tid = threadIdx.x;
  if (blockIdx.x >= TRANS_BLOCKS) {
    // ---- convert x: 8 elems per thread
    size_t i = (size_t)(blockIdx.x - TRANS_BLOCKS) * 256 + tid;
    float4 v0 = ((const float4*)x)[2 * i];
    float4 v1 = ((const float4*)x)[2 * i + 1];
    union { bf16x8 v; unsigned short u[8]; } o;
    o.u[0] = f2bf(v0.x); o.u[1] = f2bf(v0.y); o.u[2] = f2bf(v0.z); o.u[3] = f2bf(v0.w);
    o.u[4] = f2bf(v1.x); o.u[5] = f2bf(v1.y); o.u[6] = f2bf(v1.z); o.u[7] = f2bf(v1.w);
    ((bf16x8*)xb)[i] = o.v;
    return;
  }
  // ---- transpose+convert B: 64K x 256N tile
  __shared__ float tile[64][257];
  const int kt = blockIdx.x & 63;    // K/64 = 64 k-tiles
  const int nt = blockIdx.x >> 6;    // N/256 = 32 n-tiles
  const int k0 = kt * 64, n0 = nt * 256;
  const int rw  = tid >> 6;          // wave id 0..3 -> row group
  const int c4  = tid & 63;          // float4 col 0..63

#pragma unroll
  for (int p = 0; p < 16; ++p) {
    const int row = p * 4 + rw;      // wave reads 1KB contiguous
    float4 v = *(const float4*)(&B[(size_t)(k0 + row) * N_DIM + n0 + c4 * 4]);
    tile[row][c4 * 4 + 0] = v.x; tile[row][c4 * 4 + 1] = v.y;
    tile[row][c4 * 4 + 2] = v.z; tile[row][c4 * 4 + 3] = v.w;
  }
  __syncthreads();
  const int sc = tid & 7;            // k-chunk (8 k each)
  const int sr = tid >> 3;           // 0..31 n-row
#pragma unroll
  for (int it = 0; it < 8; ++it) {
    const int rn = it * 32 + sr;     // 0..255
    union { bf16x8 v; unsigned short u[8]; } o;
#pragma unroll
    for (int j = 0; j < 8; ++j) o.u[j] = f2bf(tile[sc * 8 + j][rn]);
    *(bf16x8*)(&Bt[(size_t)(n0 + rn) * K_DIM + k0 + sc * 8]) = o.v;
  }
}

// ------- bf16 MFMA GEMM: r14/r16 CHAMPION, unchanged (113.5us, MfmaUtil 25) -------
// 128x256/BK64 tile, 16 waves (4/SIMD), 3-slot counted-vmcnt ring, LDS-buffered
// vectorized epilogue. 8 structural K-loop variants + 3 epilogue-folding
// variants tested; this is the best.
template <bool FUSE>
__global__ __launch_bounds__(1024, 4) void gemm_conv_kernel(
    const unsigned short* __restrict__ Abf,   // [U][K] bf16
    const unsigned short* __restrict__ Btbf,  // [N][K] bf16
    const float* __restrict__ conv_states,    // [4][U][N]
    const float* __restrict__ conv_wts,       // [4][N]
    const float* __restrict__ conv_bias,      // [N]
    float* __restrict__ out,                  // [U][N]
    float* __restrict__ ns)                   // [4][U][N] new_states base
{
  __shared__ char smem[3 * SLOTB];   // 144KB ring; reused as 128KB C-buf

  const int orig = blockIdx.x;                    // grid 256 = 8 XCD x 32
  const int bid  = (orig & 7) * 32 + (orig >> 3); // XCD-chunked swizzle
  const int brow = bid & 7;                       // 8 row-blocks  (BM=128)
  const int bcol = bid >> 3;                      // 32 col-blocks (BN=256)
  const int tid  = threadIdx.x;
  const int lane = tid & 63;
  const int wid  = tid >> 6;             // 0..15
  const int wr = wid >> 2;               // 0..3 -> 32-row group
  const int wc = wid & 3;                // 0..3 -> 64-col group

  f32x4 acc[2][4];
#pragma unroll
  for (int m = 0; m < 2; ++m)
#pragma unroll
    for (int n = 0; n < 4; ++n)
#pragma unroll
      for (int r = 0; r < 4; ++r) acc[m][n][r] = 0.0f;

  // ---- staging: 1024 lanes x 16B = 16KB per DMA; A=1 DMA, B=2 DMAs
  const int rowa = tid >> 3;                       // 0..127
  const int gsl  = (tid & 7) ^ (rowa & 7);         // pre-swizzled global 16B slot
  const int tid16 = tid * 16;
  const unsigned short* gA0 = Abf  + (size_t)(brow * BM + rowa) * K_DIM + gsl * 8;
  const unsigned short* gB0 = Btbf + (size_t)(bcol * BN + rowa) * K_DIM + gsl * 8;
  const unsigned short* gB1 = gB0 + (size_t)128 * K_DIM;

#define STAGE(kt, base) do {                               \
    const size_t ko = (size_t)(kt) * BK;                   \
    gload_lds16(gA0 + ko, (base) + tid16);                 \
    gload_lds16(gB0 + ko, (base) + 16384 + tid16);         \
    gload_lds16(gB1 + ko, (base) + 32768 + tid16);         \
  } while (0)

  // ---- fragment read offsets (LDS rows 128B; slot^(row&7))
  const int l15 = lane & 15;
  const int fs  = lane >> 4;
  const int rsw = l15 & 7;
  int aoff[2], boff[4];
#pragma unroll
  for (int m = 0; m < 2; ++m) aoff[m] = (wr * 32 + m * 16 + l15) * 128;
#pragma unroll
  for (int n = 0; n < 4; ++n) boff[n] = (wc * 64 + n * 16 + l15) * 128;

  // ---- prologue: stage tiles 0,1; publish tile 0 (tile 1's 3 DMAs in flight)
  STAGE(0, smem);
  STAGE(1, smem + SLOTB);
  asm volatile("s_waitcnt vmcnt(3)" ::: "memory");
  __builtin_amdgcn_s_barrier();
  __builtin_amdgcn_sched_barrier(0);

  int s0 = 0, s2 = 2;   // slot of tile t, slot for tile t+2
#pragma unroll 1
  for (int t = 0; t < NT; ++t) {
    if (t + 2 < NT) STAGE(t + 2, smem + s2 * SLOTB);

    const char* curA = smem + s0 * SLOTB;
    const char* curB = curA + 16384;
#pragma unroll
    for (int kh = 0; kh < 2; ++kh) {
      const int ksl = ((kh * 4 + fs) ^ rsw) * 16;
      bf16x8 af[2], bv[4];
#pragma unroll
      for (int m = 0; m < 2; ++m) af[m] = *(const bf16x8*)(curA + aoff[m] + ksl);
#pragma unroll
      for (int n = 0; n < 4; ++n) bv[n] = *(const bf16x8*)(curB + boff[n] + ksl);
      __builtin_amdgcn_s_setprio(1);
#pragma unroll
      for (int m = 0; m < 2; ++m)
#pragma unroll
        for (int n = 0; n < 4; ++n)
          acc[m][n] = __builtin_amdgcn_mfma_f32_16x16x32_bf16(af[m], bv[n], acc[m][n], 0, 0, 0);
      __builtin_amdgcn_s_setprio(0);
    }

    if (t + 2 < NT) asm volatile("s_waitcnt vmcnt(3) lgkmcnt(0)" ::: "memory");
    else            asm volatile("s_waitcnt vmcnt(0) lgkmcnt(0)" ::: "memory");
    __builtin_amdgcn_s_barrier();
    __builtin_amdgcn_sched_barrier(0);

    s0 = (s0 == 2) ? 0 : s0 + 1;
    s2 = (s2 == 2) ? 0 : s2 + 1;
  }
#undef STAGE

  // ---- epilogue: acc -> LDS C-buf (f32 [128][256], col ^ (fs<<3)) ----
  float* cbuf = (float*)smem;
#pragma unroll
  for (int m = 0; m < 2; ++m)
#pragma unroll
    for (int n = 0; n < 4; ++n) {
      const int colb = (wc * 64 + n * 16 + l15) ^ (fs << 3);
#pragma unroll
      for (int r = 0; r < 4; ++r) {
        const int row = wr * 32 + m * 16 + fs * 4 + r;
        cbuf[row * 256 + colb] = acc[m][n][r];
      }
    }
  __syncthreads();

  // ---- streaming passes: float4 everywhere (8 passes x 1024 thr x 1 f4) ----
  const size_t PL4 = (size_t)U_DIM * (N_DIM / 4);
  const float4* cs1 = (const float4*)conv_states + PL4;
  const float4* cs2 = (const float4*)conv_states + 2 * PL4;
  const float4* cs3 = (const float4*)conv_states + 3 * PL4;
  float4* out4 = (float4*)out;
  float4* ns0 = (float4*)ns;
  float4* ns1 = ns0 + PL4;
  float4* ns2 = ns0 + 2 * PL4;
  float4* ns3 = ns0 + 3 * PL4;
  const float4* wt4 = (const float4*)conv_wts;
  const float4* bi4 = (const float4*)conv_bias;

#pragma unroll 1
  for (int i = 0; i < 8; ++i) {
    const int g    = i * 1024 + tid;
    const int lrow = g >> 6;           // 0..127
    const int d4   = g & 63;           // f4 col within 256-col tile
    const int fsr  = (lrow >> 2) & 3;  // writer's fs for this row
    const float4 xp4 = *(const float4*)&cbuf[lrow * 256 + ((d4 * 4) ^ (fsr << 3))];

    const int u = brow * BM + lrow;
    const int dcol4 = bcol * (BN / 4) + d4;
    const size_t gf4 = (size_t)u * (N_DIM / 4) + dcol4;

    const float4 w0 = wt4[dcol4];
    const float4 w1 = wt4[(N_DIM / 4) + dcol4];
    const float4 w2 = wt4[2 * (N_DIM / 4) + dcol4];
    const float4 w3 = wt4[3 * (N_DIM / 4) + dcol4];
    const float4 bs = bi4[dcol4];
    const float4 c1 = cs1[gf4];
    const float4 c2 = cs2[gf4];
    const float4 c3 = cs3[gf4];

    float4 o;
    o.x = fmaf(w0.x, c1.x, fmaf(w1.x, c2.x, fmaf(w2.x, c3.x, fmaf(w3.x, xp4.x, bs.x))));
    o.y = fmaf(w0.y, c1.y, fmaf(w1.y, c2.y, fmaf(w2.y, c3.y, fmaf(w3.y, xp4.y, bs.y))));
    o.z = fmaf(w0.z, c1.z, fmaf(w1.z, c2.z, fmaf(w2.z, c3.z, fmaf(w3.z, xp4.z, bs.z))));
    o.w = fmaf(w0.w, c1.w, fmaf(w1.w, c2.w, fmaf(w2.w, c3.w, fmaf(w3.w, xp4.w, bs.w))));

    out4[gf4] = o;
    if (FUSE) { ns0[gf4] = c1; ns1[gf4] = c2; ns2[gf4] = c3; }
    ns3[gf4] = xp4;
  }
}

extern "C" void kernel_launch(void* const* d_in, const int* in_sizes, int n_in,
                              void* d_out, int out_size, void* d_ws, size_t ws_size,
                              hipStream_t stream) {
  (void)in_sizes; (void)n_in; (void)out_size;
  const float* x           = (const float*)d_in[0];
  const float* ssm_proj    = (const float*)d_in[1];
  const float* conv_states = (const float*)d_in[2];
  const float* conv_wts    = (const float*)d_in[3];
  const float* conv_bias   = (const float*)d_in[4];
  float* outp = (float*)d_out;

  const size_t OUT_ELEMS = (size_t)U_DIM * N_DIM;        // 8M floats
  float* ns = outp + OUT_ELEMS;                          // new_states base

  const size_t BT_BYTES = (size_t)N_DIM * K_DIM * sizeof(unsigned short);  // 64MB
  const size_t XB_BYTES = (size_t)U_DIM * K_DIM * sizeof(unsigned short);  // 8MB
  const int GRID = (U_DIM / BM) * (N_DIM / BN);          // 256
  const int PREP_GRID = TRANS_BLOCKS + CONV_BLOCKS;      // 2048+2048

  if (ws_size >= BT_BYTES + XB_BYTES) {
    unsigned short* Btbf = (unsigned short*)d_ws;
    unsigned short* xbf  = (unsigned short*)((char*)d_ws + BT_BYTES);
    prep_kernel<<<PREP_GRID, 256, 0, stream>>>(ssm_proj, Btbf, x, xbf);
    gemm_conv_kernel<true><<<GRID, 1024, 0, stream>>>(
        xbf, Btbf, conv_states, conv_wts, conv_bias, outp, ns);
  } else {
    unsigned short* Btbf = (unsigned short*)ns;
    unsigned short* xbf  = (unsigned short*)(ns + 2 * OUT_ELEMS);
    prep_kernel<<<PREP_GRID, 256, 0, stream>>>(ssm_proj, Btbf, x, xbf);
    gemm_conv_kernel<false><<<GRID, 1024, 0, stream>>>(
        xbf, Btbf, conv_states, conv_wts, conv_bias, outp, ns);
    hipMemcpyAsync(ns, conv_states + OUT_ELEMS, 3 * OUT_ELEMS * sizeof(float),
                   hipMemcpyDeviceToDevice, stream);
  }
}

// Round 19
// 161.736 us; speedup vs baseline: 1.1579x; 1.0459x over previous
//
#include <hip/hip_runtime.h>
#include <hip/hip_bf16.h>

#define U_DIM 1024
#define H_DIM 4096
#define N_DIM 8192   // 2H
#define K_DIM 4096   // = H

#define BM 128
#define BN 256
#define BK 64
#define NT (K_DIM / BK)            // 64 K-tiles
#define SLOTB (BM*BK*2 + BN*BK*2)  // 16KB A + 32KB B = 49152 B per ring slot

typedef __attribute__((ext_vector_type(8))) short bf16x8;
typedef __attribute__((ext_vector_type(4))) float f32x4;

__device__ inline unsigned short f2bf(float f) {
  union { float f; unsigned u; } a; a.f = f;
  unsigned r = a.u + 0x7fffu + ((a.u >> 16) & 1u);  // RNE
  return (unsigned short)(r >> 16);
}

__device__ inline void gload_lds16(const void* g, void* l) {
  __builtin_amdgcn_global_load_lds(
      (const __attribute__((address_space(1))) unsigned*)(g),
      (__attribute__((address_space(3))) unsigned*)(l), 16, 0, 0);
}

// ------- fused pre-pass (REVERT to measured-best r14 config): -------
// ssm_proj [K][N] fp32 -> Bt [N][K] bf16 (64x64 tiles, [64][65] LDS) AND
// x -> bf16 (4 elems/thread). Widened variants (r16 8-elem conv: null;
// r18 256-col transpose: -6us) reverted.
#define TRANS_BLOCKS ((N_DIM / 64) * (K_DIM / 64))   // 8192
#define CONV_BLOCKS  ((U_DIM * H_DIM / 4) / 256)     // 4096
__global__ __launch_bounds__(256) void prep_kernel(
    const float* __restrict__ B, unsigned short* __restrict__ Bt,
    const float* __restrict__ x, unsigned short* __restrict__ xb) {
  const int tid = threadIdx.x;
  if (blockIdx.x >= TRANS_BLOCKS) {
    // ---- convert x: 4 elems per thread
    size_t i = (size_t)(blockIdx.x - TRANS_BLOCKS) * 256 + tid;
    float4 v = ((const float4*)x)[i];
    ushort4 o;
    o.x = f2bf(v.x); o.y = f2bf(v.y); o.z = f2bf(v.z); o.w = f2bf(v.w);
    ((ushort4*)xb)[i] = o;
    return;
  }
  // ---- transpose+convert B (proven path)
  __shared__ float tile[64][65];
  const int kt = blockIdx.x & 63;
  const int nt = blockIdx.x >> 6;
  const int k0 = kt * 64, n0 = nt * 64;
  const int lr = tid >> 4;
  const int lc = (tid & 15) * 4;
#pragma unroll
  for (int it = 0; it < 4; ++it) {
    int r = it * 16 + lr;
    float4 v = *(const float4*)(&B[(size_t)(k0 + r) * N_DIM + n0 + lc]);
    tile[r][lc + 0] = v.x; tile[r][lc + 1] = v.y;
    tile[r][lc + 2] = v.z; tile[r][lc + 3] = v.w;
  }
  __syncthreads();
  const int sc = tid & 7;
  const int sr = tid >> 3;
#pragma unroll
  for (int it = 0; it < 2; ++it) {
    int rn = it * 32 + sr;
    union { bf16x8 v; unsigned short u[8]; } o;
#pragma unroll
    for (int j = 0; j < 8; ++j) o.u[j] = f2bf(tile[sc * 8 + j][rn]);
    *(bf16x8*)(&Bt[(size_t)(n0 + rn) * K_DIM + k0 + sc * 8]) = o.v;
  }
}

// ------- bf16 MFMA GEMM: CHAMPION, unchanged (113.5us, MfmaUtil 25) -------
// 128x256/BK64 tile, 16 waves (4/SIMD), 3-slot counted-vmcnt ring, LDS-buffered
// vectorized epilogue. 12 structural variants tested; this is the best.
template <bool FUSE>
__global__ __launch_bounds__(1024, 4) void gemm_conv_kernel(
    const unsigned short* __restrict__ Abf,   // [U][K] bf16
    const unsigned short* __restrict__ Btbf,  // [N][K] bf16
    const float* __restrict__ conv_states,    // [4][U][N]
    const float* __restrict__ conv_wts,       // [4][N]
    const float* __restrict__ conv_bias,      // [N]
    float* __restrict__ out,                  // [U][N]
    float* __restrict__ ns)                   // [4][U][N] new_states base
{
  __shared__ char smem[3 * SLOTB];   // 144KB ring; reused as 128KB C-buf

  const int orig = blockIdx.x;                    // grid 256 = 8 XCD x 32
  const int bid  = (orig & 7) * 32 + (orig >> 3); // XCD-chunked swizzle
  const int brow = bid & 7;                       // 8 row-blocks  (BM=128)
  const int bcol = bid >> 3;                      // 32 col-blocks (BN=256)
  const int tid  = threadIdx.x;
  const int lane = tid & 63;
  const int wid  = tid >> 6;             // 0..15
  const int wr = wid >> 2;               // 0..3 -> 32-row group
  const int wc = wid & 3;                // 0..3 -> 64-col group

  f32x4 acc[2][4];
#pragma unroll
  for (int m = 0; m < 2; ++m)
#pragma unroll
    for (int n = 0; n < 4; ++n)
#pragma unroll
      for (int r = 0; r < 4; ++r) acc[m][n][r] = 0.0f;

  // ---- staging: 1024 lanes x 16B = 16KB per DMA; A=1 DMA, B=2 DMAs
  const int rowa = tid >> 3;                       // 0..127
  const int gsl  = (tid & 7) ^ (rowa & 7);         // pre-swizzled global 16B slot
  const int tid16 = tid * 16;
  const unsigned short* gA0 = Abf  + (size_t)(brow * BM + rowa) * K_DIM + gsl * 8;
  const unsigned short* gB0 = Btbf + (size_t)(bcol * BN + rowa) * K_DIM + gsl * 8;
  const unsigned short* gB1 = gB0 + (size_t)128 * K_DIM;

#define STAGE(kt, base) do {                               \
    const size_t ko = (size_t)(kt) * BK;                   \
    gload_lds16(gA0 + ko, (base) + tid16);                 \
    gload_lds16(gB0 + ko, (base) + 16384 + tid16);         \
    gload_lds16(gB1 + ko, (base) + 32768 + tid16);         \
  } while (0)

  // ---- fragment read offsets (LDS rows 128B; slot^(row&7))
  const int l15 = lane & 15;
  const int fs  = lane >> 4;
  const int rsw = l15 & 7;
  int aoff[2], boff[4];
#pragma unroll
  for (int m = 0; m < 2; ++m) aoff[m] = (wr * 32 + m * 16 + l15) * 128;
#pragma unroll
  for (int n = 0; n < 4; ++n) boff[n] = (wc * 64 + n * 16 + l15) * 128;

  // ---- prologue: stage tiles 0,1; publish tile 0 (tile 1's 3 DMAs in flight)
  STAGE(0, smem);
  STAGE(1, smem + SLOTB);
  asm volatile("s_waitcnt vmcnt(3)" ::: "memory");
  __builtin_amdgcn_s_barrier();
  __builtin_amdgcn_sched_barrier(0);

  int s0 = 0, s2 = 2;   // slot of tile t, slot for tile t+2
#pragma unroll 1
  for (int t = 0; t < NT; ++t) {
    if (t + 2 < NT) STAGE(t + 2, smem + s2 * SLOTB);

    const char* curA = smem + s0 * SLOTB;
    const char* curB = curA + 16384;
#pragma unroll
    for (int kh = 0; kh < 2; ++kh) {
      const int ksl = ((kh * 4 + fs) ^ rsw) * 16;
      bf16x8 af[2], bv[4];
#pragma unroll
      for (int m = 0; m < 2; ++m) af[m] = *(const bf16x8*)(curA + aoff[m] + ksl);
#pragma unroll
      for (int n = 0; n < 4; ++n) bv[n] = *(const bf16x8*)(curB + boff[n] + ksl);
      __builtin_amdgcn_s_setprio(1);
#pragma unroll
      for (int m = 0; m < 2; ++m)
#pragma unroll
        for (int n = 0; n < 4; ++n)
          acc[m][n] = __builtin_amdgcn_mfma_f32_16x16x32_bf16(af[m], bv[n], acc[m][n], 0, 0, 0);
      __builtin_amdgcn_s_setprio(0);
    }

    if (t + 2 < NT) asm volatile("s_waitcnt vmcnt(3) lgkmcnt(0)" ::: "memory");
    else            asm volatile("s_waitcnt vmcnt(0) lgkmcnt(0)" ::: "memory");
    __builtin_amdgcn_s_barrier();
    __builtin_amdgcn_sched_barrier(0);

    s0 = (s0 == 2) ? 0 : s0 + 1;
    s2 = (s2 == 2) ? 0 : s2 + 1;
  }
#undef STAGE

  // ---- epilogue: acc -> LDS C-buf (f32 [128][256], col ^ (fs<<3)) ----
  float* cbuf = (float*)smem;
#pragma unroll
  for (int m = 0; m < 2; ++m)
#pragma unroll
    for (int n = 0; n < 4; ++n) {
      const int colb = (wc * 64 + n * 16 + l15) ^ (fs << 3);
#pragma unroll
      for (int r = 0; r < 4; ++r) {
        const int row = wr * 32 + m * 16 + fs * 4 + r;
        cbuf[row * 256 + colb] = acc[m][n][r];
      }
    }
  __syncthreads();

  // ---- streaming passes: float4 everywhere (8 passes x 1024 thr x 1 f4) ----
  const size_t PL4 = (size_t)U_DIM * (N_DIM / 4);
  const float4* cs1 = (const float4*)conv_states + PL4;
  const float4* cs2 = (const float4*)conv_states + 2 * PL4;
  const float4* cs3 = (const float4*)conv_states + 3 * PL4;
  float4* out4 = (float4*)out;
  float4* ns0 = (float4*)ns;
  float4* ns1 = ns0 + PL4;
  float4* ns2 = ns0 + 2 * PL4;
  float4* ns3 = ns0 + 3 * PL4;
  const float4* wt4 = (const float4*)conv_wts;
  const float4* bi4 = (const float4*)conv_bias;

#pragma unroll 1
  for (int i = 0; i < 8; ++i) {
    const int g    = i * 1024 + tid;
    const int lrow = g >> 6;           // 0..127
    const int d4   = g & 63;           // f4 col within 256-col tile
    const int fsr  = (lrow >> 2) & 3;  // writer's fs for this row
    const float4 xp4 = *(const float4*)&cbuf[lrow * 256 + ((d4 * 4) ^ (fsr << 3))];

    const int u = brow * BM + lrow;
    const int dcol4 = bcol * (BN / 4) + d4;
    const size_t gf4 = (size_t)u * (N_DIM / 4) + dcol4;

    const float4 w0 = wt4[dcol4];
    const float4 w1 = wt4[(N_DIM / 4) + dcol4];
    const float4 w2 = wt4[2 * (N_DIM / 4) + dcol4];
    const float4 w3 = wt4[3 * (N_DIM / 4) + dcol4];
    const float4 bs = bi4[dcol4];
    const float4 c1 = cs1[gf4];
    const float4 c2 = cs2[gf4];
    const float4 c3 = cs3[gf4];

    float4 o;
    o.x = fmaf(w0.x, c1.x, fmaf(w1.x, c2.x, fmaf(w2.x, c3.x, fmaf(w3.x, xp4.x, bs.x))));
    o.y = fmaf(w0.y, c1.y, fmaf(w1.y, c2.y, fmaf(w2.y, c3.y, fmaf(w3.y, xp4.y, bs.y))));
    o.z = fmaf(w0.z, c1.z, fmaf(w1.z, c2.z, fmaf(w2.z, c3.z, fmaf(w3.z, xp4.z, bs.z))));
    o.w = fmaf(w0.w, c1.w, fmaf(w1.w, c2.w, fmaf(w2.w, c3.w, fmaf(w3.w, xp4.w, bs.w))));

    out4[gf4] = o;
    if (FUSE) { ns0[gf4] = c1; ns1[gf4] = c2; ns2[gf4] = c3; }
    ns3[gf4] = xp4;
  }
}

extern "C" void kernel_launch(void* const* d_in, const int* in_sizes, int n_in,
                              void* d_out, int out_size, void* d_ws, size_t ws_size,
                              hipStream_t stream) {
  (void)in_sizes; (void)n_in; (void)out_size;
  const float* x           = (const float*)d_in[0];
  const float* ssm_proj    = (const float*)d_in[1];
  const float* conv_states = (const float*)d_in[2];
  const float* conv_wts    = (const float*)d_in[3];
  const float* conv_bias   = (const float*)d_in[4];
  float* outp = (float*)d_out;

  const size_t OUT_ELEMS = (size_t)U_DIM * N_DIM;        // 8M floats
  float* ns = outp + OUT_ELEMS;                          // new_states base

  const size_t BT_BYTES = (size_t)N_DIM * K_DIM * sizeof(unsigned short);  // 64MB
  const size_t XB_BYTES = (size_t)U_DIM * K_DIM * sizeof(unsigned short);  // 8MB
  const int GRID = (U_DIM / BM) * (N_DIM / BN);          // 256
  const int PREP_GRID = TRANS_BLOCKS + CONV_BLOCKS;      // 8192+4096

  if (ws_size >= BT_BYTES + XB_BYTES) {
    unsigned short* Btbf = (unsigned short*)d_ws;
    unsigned short* xbf  = (unsigned short*)((char*)d_ws + BT_BYTES);
    prep_kernel<<<PREP_GRID, 256, 0, stream>>>(ssm_proj, Btbf, x, xbf);
    gemm_conv_kernel<true><<<GRID, 1024, 0, stream>>>(
        xbf, Btbf, conv_states, conv_wts, conv_bias, outp, ns);
  } else {
    unsigned short* Btbf = (unsigned short*)ns;
    unsigned short* xbf  = (unsigned short*)(ns + 2 * OUT_ELEMS);
    prep_kernel<<<PREP_GRID, 256, 0, stream>>>(ssm_proj, Btbf, x, xbf);
    gemm_conv_kernel<false><<<GRID, 1024, 0, stream>>>(
        xbf, Btbf, conv_states, conv_wts, conv_bias, outp, ns);
    hipMemcpyAsync(ns, conv_states + OUT_ELEMS, 3 * OUT_ELEMS * sizeof(float),
                   hipMemcpyDeviceToDevice, stream);
  }
}